// Round 9
// baseline (323.582 us; speedup 1.0000x reference)
//
#include <hip/hip_runtime.h>
#include <hip/hip_bf16.h>
#include <stdint.h>

using bf16 = __hip_bfloat16;
typedef __bf16 bf16x8 __attribute__((ext_vector_type(8)));
typedef float f32x4 __attribute__((ext_vector_type(4)));
typedef float f32x16 __attribute__((ext_vector_type(16)));
typedef short short8 __attribute__((ext_vector_type(8)));

#define GLD_LDS16(gp, lp)                                                            \
  __builtin_amdgcn_global_load_lds(                                                  \
      (const __attribute__((address_space(1))) unsigned int*)(gp),                   \
      (__attribute__((address_space(3))) unsigned int*)(lp), 16, 0, 0)

// ---------------- x (f32) -> bf16 ----------------
__global__ __launch_bounds__(256) void convert_x_kernel(const float* __restrict__ x,
                                                        bf16* __restrict__ xb, int n)
{
  for (int i = (blockIdx.x * 256 + threadIdx.x) * 8; i < n; i += gridDim.x * 256 * 8) {
    float4 a = *(const float4*)(x + i);
    float4 b = *(const float4*)(x + i + 4);
    union { bf16 h[8]; short8 v; } u;
    u.h[0] = __float2bfloat16(a.x);
    u.h[1] = __float2bfloat16(a.y);
    u.h[2] = __float2bfloat16(a.z);
    u.h[3] = __float2bfloat16(a.w);
    u.h[4] = __float2bfloat16(b.x);
    u.h[5] = __float2bfloat16(b.y);
    u.h[6] = __float2bfloat16(b.z);
    u.h[7] = __float2bfloat16(b.w);
    *(short8*)(xb + i) = u.v;
  }
}

// ---------------- U -> bf16, SVtT[i][r] = S[r]*Vt[r][i] (bf16) ----------------
__global__ __launch_bounds__(256) void prep_kernel(const float* __restrict__ U,
                                                   const float* __restrict__ S,
                                                   const float* __restrict__ Vt,
                                                   bf16* __restrict__ Ub,
                                                   bf16* __restrict__ SVtT)
{
  int t = blockIdx.x * 256 + threadIdx.x;
  if (t < 4096 * 128) {
    Ub[t] = __float2bfloat16(U[t]);
    int i = t >> 7, r = t & 127;
    SVtT[t] = __float2bfloat16(S[r] * Vt[r * 4096 + i]);
  }
}

// ---------------- wbuild v2: 128x128, K=128 staged in ONE shot ----------------
__global__ __launch_bounds__(256, 2) void gemm_wbuild(const bf16* __restrict__ A,
                                                      const bf16* __restrict__ B,
                                                      bf16* __restrict__ Cb,
                                                      int M, int N, int K,
                                                      const int* __restrict__ indices,
                                                      const float* __restrict__ centroids,
                                                      const float* __restrict__ wscale,
                                                      const float* __restrict__ wbias)
{
  __shared__ bf16 As4[4 * 4096];   // 4 chunks x 128 rows x 32 k = 32 KB
  __shared__ bf16 Bs4[4 * 4096];   // 32 KB

  const int tid  = threadIdx.x;
  const int m0   = blockIdx.y * 128;
  const int n0   = blockIdx.x * 128;
  const int wid  = tid >> 6;
  const int lane = tid & 63;
  const int wm   = wid >> 1;
  const int wn   = wid & 1;
  const int kk   = (lane >> 4) * 8;
  const int fr   = lane & 15;

  const int sr = tid >> 2;          // 0..63
  const int sc = (tid & 3) * 8;     // 0,8,16,24
  const bf16* ga = A + (size_t)(m0 + sr) * 128 + sc;
  const bf16* gb = B + (size_t)(n0 + sr) * 128 + sc;

#pragma unroll
  for (int c = 0; c < 4; c++) {
    GLD_LDS16(ga + 32 * c,            &As4[c * 4096 + tid * 8]);
    GLD_LDS16(ga + 32 * c + 64 * 128, &As4[c * 4096 + 2048 + tid * 8]);
    GLD_LDS16(gb + 32 * c,            &Bs4[c * 4096 + tid * 8]);
    GLD_LDS16(gb + 32 * c + 64 * 128, &Bs4[c * 4096 + 2048 + tid * 8]);
  }
  __syncthreads();   // drains vmcnt -> all 64 KB staged

  f32x4 acc[4][4] = {};
#pragma unroll
  for (int c = 0; c < 4; c++) {
    bf16x8 af[4], bfr[4];
#pragma unroll
    for (int m = 0; m < 4; m++)
      af[m] = *(const bf16x8*)(&As4[c * 4096 + (wm * 64 + m * 16 + fr) * 32 + kk]);
#pragma unroll
    for (int n = 0; n < 4; n++)
      bfr[n] = *(const bf16x8*)(&Bs4[c * 4096 + (wn * 64 + n * 16 + fr) * 32 + kk]);
#pragma unroll
    for (int m = 0; m < 4; m++)
#pragma unroll
      for (int n = 0; n < 4; n++)
        acc[m][n] = __builtin_amdgcn_mfma_f32_16x16x32_bf16(af[m], bfr[n], acc[m][n], 0, 0, 0);
  }

#pragma unroll
  for (int m = 0; m < 4; m++) {
#pragma unroll
    for (int n = 0; n < 4; n++) {
      const int col  = n0 + wn * 64 + n * 16 + (lane & 15);
      const int rowb = m0 + wm * 64 + m * 16 + (lane >> 4) * 4;
#pragma unroll
      for (int j = 0; j < 4; j++) {
        const int row  = rowb + j;
        const int idxv = indices[row * 512 + (col >> 3)];
        const float cv = centroids[idxv * 8 + (col & 7)];
        const float w  = cv * wscale[row] + wbias[row] + acc[m][n][j];
        Cb[(size_t)row * N + col] = __float2bfloat16(w);
      }
    }
  }
}

// ---------------- main 256x256 pipelined GEMM, 32x32x16 MFMA ----------------
// R6 schedule verbatim (barriers, stage order, vmcnt(4), b0r re-read, aq1 at
// p1-post — all proven race-free at 230 us). Per-phase ds_read counts and byte
// regions identical; only the fragment geometry / MFMA shape / epilogue change:
//  * 32x32x16 bf16 MFMA: measured 2495 TF vs 2176 (16x16) -> wall 2483->2065 cyc
//  * A-frag: row = base + (lane&31), k = ks*16 + (lane>>5)*8  (8 b128/quadrant)
//  * B-frag: col = base + (lane&31), same k split              (4 b128/quadrant)
//  * C/D: col = lane&31, row = (reg&3) + 8*(reg>>2) + 4*(lane>>5)  [m74/m101]
//  NOTE (R7 lesson): do NOT remove p2's b0r re-read or move aq1 to p0-post —
//  doubled FETCH_SIZE and halved throughput.
__global__ __launch_bounds__(512, 2) void gemm256(const bf16* __restrict__ A,
                                                  const bf16* __restrict__ B,
                                                  float* __restrict__ C,
                                                  const float* __restrict__ bias)
{
  extern __shared__ char smem[];     // [2][A 32KB | B 32KB] = 128 KiB
  constexpr int K = 4096;
  constexpr int N = 4096;

  const int tid  = threadIdx.x;
  const int lane = tid & 63;
  const int wave = tid >> 6;
  const int wm   = wave >> 2;        // 0..1
  const int wn   = wave & 3;         // 0..3
  const int lr   = lane & 31;        // fragment row/col within 32
  const int kh   = (lane >> 5) * 8;  // k-half offset
  const int swx  = (lane & 7) << 4;  // read-side swizzle (row&7 == lane&7)

  // XCD-aware swizzle, 8x8 tile group per XCD: grid m=32, n=16
  const int bid = blockIdx.x;
  const int xcd = bid & 7;
  const int idx = bid >> 3;
  const int mi  = (xcd & 3) * 8 + (idx & 7);
  const int ni  = (xcd >> 2) * 8 + (idx >> 3);
  const int m0  = mi * 256;
  const int n0  = ni * 256;

  // stage bases: inverse-swizzled global source for linear global_load_lds dest.
  const int pA = tid * 16;
  const int rA = pA >> 7;
  const int kA = ((pA ^ ((rA & 7) << 4)) & 127) >> 1;
  const bf16* gA0 = A + (size_t)(m0 + rA) * K + kA;
  const int pB = (tid >> 8) * 8192 + (tid & 255) * 16;
  const int rB = pB >> 7;
  const int kB = ((pB ^ ((rB & 7) << 4)) & 127) >> 1;
  const bf16* gB0 = B + (size_t)(n0 + rB) * K + kB;

  f32x16 acc[4][2] = {};   // [qm*2+mm][qn] of 32x32 fragments

  // slot (rowdelta, lds-byte-delta): A: s0(0,0) s1(128,16384) s2(64,8192) s3(192,24576)
  //                                  B: s0(0,0) s1(128,16384) s2(32,4096) s3(160,20480)
  // gA_p tracks tile t+2's k for A stages; gB_p tracks tile t+1's k (B2/B3: +64).
#define STG_A0(bo) GLD_LDS16(gA_p,                   smem + (bo) + pA)
#define STG_A1(bo) GLD_LDS16(gA_p + 128 * 4096,      smem + (bo) + pA + 16384)
#define STG_A2(bo) GLD_LDS16(gA_p +  64 * 4096,      smem + (bo) + pA + 8192)
#define STG_A3(bo) GLD_LDS16(gA_p + 192 * 4096,      smem + (bo) + pA + 24576)
#define STG_B0(bo) GLD_LDS16(gB_p,                   smem + (bo) + 32768 + pB)
#define STG_B1(bo) GLD_LDS16(gB_p + 128 * 4096,      smem + (bo) + 32768 + pB + 16384)
#define STG_B2(bo) GLD_LDS16(gB_p + 64 +  32 * 4096, smem + (bo) + 32768 + pB + 4096)
#define STG_B3(bo) GLD_LDS16(gB_p + 64 + 160 * 4096, smem + (bo) + 32768 + pB + 20480)

  // A quadrant: 2 row-fragments x 4 k-steps = 8 ds_read_b128 (same as R6)
#define LOAD_AQ(dst, qm, bo)                                                        \
  _Pragma("unroll") for (int mm = 0; mm < 2; mm++)                                  \
    _Pragma("unroll") for (int ks = 0; ks < 4; ks++)                                \
      dst[mm][ks] = *(const bf16x8*)(smem + (bo) +                                  \
          ((((wm * 128 + (qm) * 64 + mm * 32 + lr) * 128) +                         \
            (ks * 16 + kh) * 2) ^ swx));

  // B quadrant: 1 col-fragment x 4 k-steps = 4 ds_read_b128 (same as R6)
#define LOAD_BQ(dst, qn, bo)                                                        \
  _Pragma("unroll") for (int ks = 0; ks < 4; ks++)                                  \
    dst[ks] = *(const bf16x8*)(smem + (bo) + 32768 +                                \
        ((((wn * 64 + (qn) * 32 + lr) * 128) +                                      \
          (ks * 16 + kh) * 2) ^ swx));

  // 8 x v_mfma_f32_32x32x16_bf16 per cluster (2 independent acc chains)
#define CLUSTER(qm, qn, av, bv)                                                     \
  __builtin_amdgcn_s_setprio(1);                                                    \
  _Pragma("unroll") for (int ks = 0; ks < 4; ks++)                                  \
    _Pragma("unroll") for (int mm = 0; mm < 2; mm++)                                \
      acc[(qm) * 2 + mm][qn] =                                                      \
          __builtin_amdgcn_mfma_f32_32x32x16_bf16(                                  \
              av[mm][ks], bv[ks], acc[(qm) * 2 + mm][qn], 0, 0, 0);                 \
  __builtin_amdgcn_s_setprio(0);

#define SBAR   __builtin_amdgcn_s_barrier()
#define SCHED0 __builtin_amdgcn_sched_barrier(0)
#define VM4    asm volatile("s_waitcnt vmcnt(4)" ::: "memory")

  bf16x8 aq0[2][4], aq1[2][4], b0[4], b1[4], b0r[4];

  // prologue: tile0 all 8 slots -> buf0; tile1 (k=64) A0A1/B2B3/A2A3 -> buf1.
  // vmcnt(6) leaves exactly tile1's 6 loads in flight -> tile0's 8 landed.
  GLD_LDS16(gA0,                  smem + pA);
  GLD_LDS16(gA0 + 128 * 4096,     smem + pA + 16384);
  GLD_LDS16(gB0,                  smem + 32768 + pB);
  GLD_LDS16(gB0 + 128 * 4096,     smem + 32768 + pB + 16384);
  GLD_LDS16(gB0 +  32 * 4096,     smem + 32768 + pB + 4096);
  GLD_LDS16(gB0 + 160 * 4096,     smem + 32768 + pB + 20480);
  GLD_LDS16(gA0 +  64 * 4096,     smem + pA + 8192);
  GLD_LDS16(gA0 + 192 * 4096,     smem + pA + 24576);
  GLD_LDS16(gA0 + 64,             smem + 65536 + pA);
  GLD_LDS16(gA0 + 64 + 128 * 4096, smem + 65536 + pA + 16384);
  GLD_LDS16(gB0 + 64 +  32 * 4096, smem + 65536 + 32768 + pB + 4096);
  GLD_LDS16(gB0 + 64 + 160 * 4096, smem + 65536 + 32768 + pB + 20480);
  GLD_LDS16(gA0 + 64 +  64 * 4096, smem + 65536 + pA + 8192);
  GLD_LDS16(gA0 + 64 + 192 * 4096, smem + 65536 + pA + 24576);
  asm volatile("s_waitcnt vmcnt(6)" ::: "memory");
  SBAR;
  LOAD_AQ(aq0, 0, 0);
  LOAD_BQ(b0, 0, 0);
  SCHED0;

  const bf16* gA_p = gA0 + 128;        // tile t+2 (t=0) k offset
  const bf16* gB_p = gB0 + 64;         // tile t+1 (t=0) k offset

#define TILE(AB, NB)                                                                \
  {                                                                                 \
    /* p0 (qm0,qn0): stage B0B1(t+1)->NB; pre-load b1 (B2B3 of t) */                \
    SBAR;                                                                           \
    STG_B0(NB); STG_B1(NB);                                                         \
    LOAD_BQ(b1, 1, AB);                                                             \
    SCHED0;                                                                         \
    CLUSTER(0, 0, aq0, b0);                                                         \
    SCHED0;                                                                         \
    /* p1 (qm0,qn1): stage A0A1(t+2)->AB; post-load aq1 (A2A3 of t) */              \
    SBAR;                                                                           \
    STG_A0(AB); STG_A1(AB);                                                         \
    SCHED0;                                                                         \
    CLUSTER(0, 1, aq0, b1);                                                         \
    SCHED0;                                                                         \
    LOAD_AQ(aq1, 1, AB);                                                            \
    SCHED0;                                                                         \
    /* p2 (qm1,qn1): stage B2B3(t+2)->AB; pre-load b0r (B0B1 of t) */               \
    SBAR;                                                                           \
    STG_B2(AB); STG_B3(AB);                                                         \
    LOAD_BQ(b0r, 0, AB);                                                            \
    SCHED0;                                                                         \
    CLUSTER(1, 1, aq1, b1);                                                         \
    SCHED0;                                                                         \
    /* p3 (qm1,qn0): vmcnt(4) forces <= t.p0 landed; post-load next tile's aq0,b0 */\
    VM4;                                                                            \
    SBAR;                                                                           \
    STG_A2(AB); STG_A3(AB);                                                         \
    SCHED0;                                                                         \
    CLUSTER(1, 0, aq1, b0r);                                                        \
    SCHED0;                                                                         \
    LOAD_AQ(aq0, 0, NB);                                                            \
    LOAD_BQ(b0, 0, NB);                                                             \
    SCHED0;                                                                         \
    gA_p += 64; gB_p += 64;                                                         \
  }

  for (int tt = 0; tt < 32; tt++) {
    TILE(0, 65536);
    TILE(65536, 0);
  }

  // epilogue: 32x32 C/D layout: col = lane&31, row = (reg&3) + 8*(reg>>2) + 4*(lane>>5)
#pragma unroll
  for (int mf = 0; mf < 4; mf++) {
#pragma unroll
    for (int nf = 0; nf < 2; nf++) {
      const int col  = n0 + wn * 64 + nf * 32 + lr;
      const int rowb = m0 + wm * 128 + mf * 32 + (lane >> 5) * 4;
      const float bv = bias[col];
#pragma unroll
      for (int r = 0; r < 16; r++) {
        const int row = rowb + (r & 3) + 8 * (r >> 2);
        C[(size_t)row * N + col] = acc[mf][nf][r] + bv;
      }
    }
  }
#undef TILE
#undef CLUSTER
#undef LOAD_AQ
#undef LOAD_BQ
#undef SBAR
#undef SCHED0
#undef VM4
#undef STG_A0
#undef STG_A1
#undef STG_A2
#undef STG_A3
#undef STG_B0
#undef STG_B1
#undef STG_B2
#undef STG_B3
}

extern "C" void kernel_launch(void* const* d_in, const int* in_sizes, int n_in,
                              void* d_out, int out_size, void* d_ws, size_t ws_size,
                              hipStream_t stream)
{
  const float* x         = (const float*)d_in[0];
  const float* centroids = (const float*)d_in[1];
  const int*   indices   = (const int*)d_in[2];
  const float* U         = (const float*)d_in[3];
  const float* S         = (const float*)d_in[4];
  const float* Vt        = (const float*)d_in[5];
  const float* wscale    = (const float*)d_in[6];
  const float* wbias     = (const float*)d_in[7];
  const float* bias      = (const float*)d_in[8];
  float* out = (float*)d_out;

  char* ws = (char*)d_ws;
  bf16* xb   = (bf16*)(ws);                          // 64 MB
  bf16* Wb   = (bf16*)(ws + 67108864);               // 32 MB
  bf16* Ub   = (bf16*)(ws + 100663296);              // 1 MB
  bf16* SVtT = (bf16*)(ws + 101711872);              // 1 MB

  convert_x_kernel<<<2048, 256, 0, stream>>>(x, xb, 8192 * 4096);
  prep_kernel<<<2048, 256, 0, stream>>>(U, S, Vt, Ub, SVtT);

  // W[o][i] = codebook(o,i)*wscale[o] + wbias[o] + sum_r Ub[o][r]*SVtT[i][r]
  dim3 gW(4096 / 128, 4096 / 128);
  gemm_wbuild<<<gW, 256, 0, stream>>>(Ub, SVtT, Wb, 4096, 4096, 128,
                                      indices, centroids, wscale, wbias);

  // out[t][o] = sum_i xb[t][i]*Wb[o][i] + bias[o]
  gemm256<<<512, 512, 131072, stream>>>(xb, Wb, out, bias);
}

// Round 10
// 288.342 us; speedup vs baseline: 1.1222x; 1.1222x over previous
//
#include <hip/hip_runtime.h>
#include <hip/hip_bf16.h>
#include <stdint.h>

using bf16 = __hip_bfloat16;
typedef __bf16 bf16x8 __attribute__((ext_vector_type(8)));
typedef float f32x4 __attribute__((ext_vector_type(4)));
typedef short short8 __attribute__((ext_vector_type(8)));

#define GLD_LDS16(gp, lp)                                                            \
  __builtin_amdgcn_global_load_lds(                                                  \
      (const __attribute__((address_space(1))) unsigned int*)(gp),                   \
      (__attribute__((address_space(3))) unsigned int*)(lp), 16, 0, 0)

// ---------------- x (f32) -> bf16 ----------------
__global__ __launch_bounds__(256) void convert_x_kernel(const float* __restrict__ x,
                                                        bf16* __restrict__ xb, int n)
{
  for (int i = (blockIdx.x * 256 + threadIdx.x) * 8; i < n; i += gridDim.x * 256 * 8) {
    float4 a = *(const float4*)(x + i);
    float4 b = *(const float4*)(x + i + 4);
    union { bf16 h[8]; short8 v; } u;
    u.h[0] = __float2bfloat16(a.x);
    u.h[1] = __float2bfloat16(a.y);
    u.h[2] = __float2bfloat16(a.z);
    u.h[3] = __float2bfloat16(a.w);
    u.h[4] = __float2bfloat16(b.x);
    u.h[5] = __float2bfloat16(b.y);
    u.h[6] = __float2bfloat16(b.z);
    u.h[7] = __float2bfloat16(b.w);
    *(short8*)(xb + i) = u.v;
  }
}

// ---------------- U -> bf16, SVtT[i][r] = S[r]*Vt[r][i] (bf16) ----------------
__global__ __launch_bounds__(256) void prep_kernel(const float* __restrict__ U,
                                                   const float* __restrict__ S,
                                                   const float* __restrict__ Vt,
                                                   bf16* __restrict__ Ub,
                                                   bf16* __restrict__ SVtT)
{
  int t = blockIdx.x * 256 + threadIdx.x;
  if (t < 4096 * 128) {
    Ub[t] = __float2bfloat16(U[t]);
    int i = t >> 7, r = t & 127;
    SVtT[t] = __float2bfloat16(S[r] * Vt[r * 4096 + i]);
  }
}

// ---------------- wbuild v2: 128x128, K=128 staged in ONE shot ----------------
__global__ __launch_bounds__(256, 2) void gemm_wbuild(const bf16* __restrict__ A,
                                                      const bf16* __restrict__ B,
                                                      bf16* __restrict__ Cb,
                                                      int M, int N, int K,
                                                      const int* __restrict__ indices,
                                                      const float* __restrict__ centroids,
                                                      const float* __restrict__ wscale,
                                                      const float* __restrict__ wbias)
{
  __shared__ bf16 As4[4 * 4096];   // 4 chunks x 128 rows x 32 k = 32 KB
  __shared__ bf16 Bs4[4 * 4096];   // 32 KB

  const int tid  = threadIdx.x;
  const int m0   = blockIdx.y * 128;
  const int n0   = blockIdx.x * 128;
  const int wid  = tid >> 6;
  const int lane = tid & 63;
  const int wm   = wid >> 1;
  const int wn   = wid & 1;
  const int kk   = (lane >> 4) * 8;
  const int fr   = lane & 15;

  const int sr = tid >> 2;          // 0..63
  const int sc = (tid & 3) * 8;     // 0,8,16,24
  const bf16* ga = A + (size_t)(m0 + sr) * 128 + sc;
  const bf16* gb = B + (size_t)(n0 + sr) * 128 + sc;

#pragma unroll
  for (int c = 0; c < 4; c++) {
    GLD_LDS16(ga + 32 * c,            &As4[c * 4096 + tid * 8]);
    GLD_LDS16(ga + 32 * c + 64 * 128, &As4[c * 4096 + 2048 + tid * 8]);
    GLD_LDS16(gb + 32 * c,            &Bs4[c * 4096 + tid * 8]);
    GLD_LDS16(gb + 32 * c + 64 * 128, &Bs4[c * 4096 + 2048 + tid * 8]);
  }
  __syncthreads();   // drains vmcnt -> all 64 KB staged

  f32x4 acc[4][4] = {};
#pragma unroll
  for (int c = 0; c < 4; c++) {
    bf16x8 af[4], bfr[4];
#pragma unroll
    for (int m = 0; m < 4; m++)
      af[m] = *(const bf16x8*)(&As4[c * 4096 + (wm * 64 + m * 16 + fr) * 32 + kk]);
#pragma unroll
    for (int n = 0; n < 4; n++)
      bfr[n] = *(const bf16x8*)(&Bs4[c * 4096 + (wn * 64 + n * 16 + fr) * 32 + kk]);
#pragma unroll
    for (int m = 0; m < 4; m++)
#pragma unroll
      for (int n = 0; n < 4; n++)
        acc[m][n] = __builtin_amdgcn_mfma_f32_16x16x32_bf16(af[m], bfr[n], acc[m][n], 0, 0, 0);
  }

#pragma unroll
  for (int m = 0; m < 4; m++) {
#pragma unroll
    for (int n = 0; n < 4; n++) {
      const int col  = n0 + wn * 64 + n * 16 + (lane & 15);
      const int rowb = m0 + wm * 64 + m * 16 + (lane >> 4) * 4;
#pragma unroll
      for (int j = 0; j < 4; j++) {
        const int row  = rowb + j;
        const int idxv = indices[row * 512 + (col >> 3)];
        const float cv = centroids[idxv * 8 + (col & 7)];
        const float w  = cv * wscale[row] + wbias[row] + acc[m][n][j];
        Cb[(size_t)row * N + col] = __float2bfloat16(w);
      }
    }
  }
}

// ---------------- main 256x256 pipelined GEMM, 16x16x32 MFMA ----------------
// R6 schedule verbatim (proven 230 us, race-free). New this round: base-pointer
// + literal-offset ds_read addressing. Decomposition (exact, since swx only
// touches bits 4-6 and row*128 only bits >=7):
//   addr = base(buf,ks) + Rlit*128,  base = smem + buf*65536 (+32768 B)
//          + w*quadstride + fr*128 + ((ks*64 + kk*2) ^ swx)
// -> 8 loop-invariant bases; every fragment read = ds_read_b128 base offset:LIT.
// R9 lesson: 32x32x16 MFMA = 4-way bank conflict under this layout (2.96e7) — reverted.
// R7 lesson: do NOT remove p2's b0r re-read or move aq1 to p0-post.
__global__ __launch_bounds__(512, 2) void gemm256(const bf16* __restrict__ A,
                                                  const bf16* __restrict__ B,
                                                  float* __restrict__ C,
                                                  const float* __restrict__ bias)
{
  extern __shared__ char smem[];     // [2][A 32KB | B 32KB] = 128 KiB
  constexpr int K = 4096;
  constexpr int N = 4096;

  const int tid  = threadIdx.x;
  const int lane = tid & 63;
  const int wave = tid >> 6;
  const int wm   = wave >> 2;        // 0..1
  const int wn   = wave & 3;         // 0..3
  const int fr   = lane & 15;
  const int kk   = (lane >> 4) * 8;
  const int swx  = (fr & 7) << 4;    // read-side swizzle

  // XCD-aware swizzle, 8x8 tile group per XCD: grid m=32, n=16
  const int bid = blockIdx.x;
  const int xcd = bid & 7;
  const int idx = bid >> 3;
  const int mi  = (xcd & 3) * 8 + (idx & 7);
  const int ni  = (xcd >> 2) * 8 + (idx >> 3);
  const int m0  = mi * 256;
  const int n0  = ni * 256;

  // stage bases: inverse-swizzled global source for linear global_load_lds dest.
  const int pA = tid * 16;
  const int rA = pA >> 7;
  const int kA = ((pA ^ ((rA & 7) << 4)) & 127) >> 1;
  const bf16* gA0 = A + (size_t)(m0 + rA) * K + kA;
  const int pB = (tid >> 8) * 8192 + (tid & 255) * 16;
  const int rB = pB >> 7;
  const int kB = ((pB ^ ((rB & 7) << 4)) & 127) >> 1;
  const bf16* gB0 = B + (size_t)(n0 + rB) * K + kB;

  f32x4 acc[8][4] = {};

  // loop-invariant LDS read bases (8 pointers; ks = k-half 0/1, buf 0/1)
  const int laneK0 = fr * 128 + ((kk * 2) ^ swx);
  const int laneK1 = fr * 128 + ((64 + kk * 2) ^ swx);
  const char* bA00 = smem + wm * 16384 + laneK0;            // buf0, ks0
  const char* bA01 = smem + wm * 16384 + laneK1;            // buf0, ks1
  const char* bA10 = bA00 + 65536;                          // buf1
  const char* bA11 = bA01 + 65536;
  const char* bB00 = smem + 32768 + wn * 8192 + laneK0;
  const char* bB01 = smem + 32768 + wn * 8192 + laneK1;
  const char* bB10 = bB00 + 65536;
  const char* bB11 = bB01 + 65536;

  // slot (rowdelta, lds-byte-delta): A: s0(0,0) s1(128,16384) s2(64,8192) s3(192,24576)
  //                                  B: s0(0,0) s1(128,16384) s2(32,4096) s3(160,20480)
  // gA_p tracks tile t+2's k for A stages; gB_p tracks tile t+1's k (B2/B3: +64).
#define STG_A0(bo) GLD_LDS16(gA_p,                   smem + (bo) + pA)
#define STG_A1(bo) GLD_LDS16(gA_p + 128 * 4096,      smem + (bo) + pA + 16384)
#define STG_A2(bo) GLD_LDS16(gA_p +  64 * 4096,      smem + (bo) + pA + 8192)
#define STG_A3(bo) GLD_LDS16(gA_p + 192 * 4096,      smem + (bo) + pA + 24576)
#define STG_B0(bo) GLD_LDS16(gB_p,                   smem + (bo) + 32768 + pB)
#define STG_B1(bo) GLD_LDS16(gB_p + 128 * 4096,      smem + (bo) + 32768 + pB + 16384)
#define STG_B2(bo) GLD_LDS16(gB_p + 64 +  32 * 4096, smem + (bo) + 32768 + pB + 4096)
#define STG_B3(bo) GLD_LDS16(gB_p + 64 + 160 * 4096, smem + (bo) + 32768 + pB + 20480)

  // fragment loads: base pointer + pure-literal offset -> ds_read offset:imm
#define LOAD_AQ(dst, qm, P0, P1)                                                    \
  _Pragma("unroll") for (int mm = 0; mm < 4; mm++)                                  \
    _Pragma("unroll") for (int ks = 0; ks < 2; ks++)                                \
      dst[mm][ks] = *(const bf16x8*)((ks ? (P1) : (P0)) +                           \
                                     ((qm) * 8192 + mm * 2048));

#define LOAD_BQ(dst, qn, P0, P1)                                                    \
  _Pragma("unroll") for (int nn = 0; nn < 2; nn++)                                  \
    _Pragma("unroll") for (int ks = 0; ks < 2; ks++)                                \
      dst[nn][ks] = *(const bf16x8*)((ks ? (P1) : (P0)) +                           \
                                     ((qn) * 4096 + nn * 2048));

#define CLUSTER(qm, qn, av, bv)                                                     \
  __builtin_amdgcn_s_setprio(1);                                                    \
  _Pragma("unroll") for (int ks = 0; ks < 2; ks++)                                  \
    _Pragma("unroll") for (int mm = 0; mm < 4; mm++)                                \
      _Pragma("unroll") for (int nn = 0; nn < 2; nn++)                              \
        acc[(qm) * 4 + mm][(qn) * 2 + nn] =                                         \
            __builtin_amdgcn_mfma_f32_16x16x32_bf16(                                \
                av[mm][ks], bv[nn][ks], acc[(qm) * 4 + mm][(qn) * 2 + nn],          \
                0, 0, 0);                                                           \
  __builtin_amdgcn_s_setprio(0);

#define SBAR   __builtin_amdgcn_s_barrier()
#define SCHED0 __builtin_amdgcn_sched_barrier(0)
#define VM4    asm volatile("s_waitcnt vmcnt(4)" ::: "memory")

  bf16x8 aq0[4][2], aq1[4][2], b0[2][2], b1[2][2], b0r[2][2];

  // prologue: tile0 all 8 slots -> buf0; tile1 (k=64) A0A1/B2B3/A2A3 -> buf1.
  // vmcnt(6) leaves exactly tile1's 6 loads in flight -> tile0's 8 landed.
  GLD_LDS16(gA0,                  smem + pA);
  GLD_LDS16(gA0 + 128 * 4096,     smem + pA + 16384);
  GLD_LDS16(gB0,                  smem + 32768 + pB);
  GLD_LDS16(gB0 + 128 * 4096,     smem + 32768 + pB + 16384);
  GLD_LDS16(gB0 +  32 * 4096,     smem + 32768 + pB + 4096);
  GLD_LDS16(gB0 + 160 * 4096,     smem + 32768 + pB + 20480);
  GLD_LDS16(gA0 +  64 * 4096,     smem + pA + 8192);
  GLD_LDS16(gA0 + 192 * 4096,     smem + pA + 24576);
  GLD_LDS16(gA0 + 64,             smem + 65536 + pA);
  GLD_LDS16(gA0 + 64 + 128 * 4096, smem + 65536 + pA + 16384);
  GLD_LDS16(gB0 + 64 +  32 * 4096, smem + 65536 + 32768 + pB + 4096);
  GLD_LDS16(gB0 + 64 + 160 * 4096, smem + 65536 + 32768 + pB + 20480);
  GLD_LDS16(gA0 + 64 +  64 * 4096, smem + 65536 + pA + 8192);
  GLD_LDS16(gA0 + 64 + 192 * 4096, smem + 65536 + pA + 24576);
  asm volatile("s_waitcnt vmcnt(6)" ::: "memory");
  SBAR;
  LOAD_AQ(aq0, 0, bA00, bA01);
  LOAD_BQ(b0, 0, bB00, bB01);
  SCHED0;

  const bf16* gA_p = gA0 + 128;        // tile t+2 (t=0) k offset
  const bf16* gB_p = gB0 + 64;         // tile t+1 (t=0) k offset

  // TILE(AB, NB, ABa0,ABa1,ABb0,ABb1 = this-buffer bases; NBa0..NBb1 = other)
#define TILE(AB, NB, ABa0, ABa1, ABb0, ABb1, NBa0, NBa1, NBb0, NBb1)                \
  {                                                                                 \
    /* p0 (qm0,qn0): stage B0B1(t+1)->NB; pre-load b1 (B2B3 of t) */                \
    SBAR;                                                                           \
    STG_B0(NB); STG_B1(NB);                                                         \
    LOAD_BQ(b1, 1, ABb0, ABb1);                                                     \
    SCHED0;                                                                         \
    CLUSTER(0, 0, aq0, b0);                                                         \
    SCHED0;                                                                         \
    /* p1 (qm0,qn1): stage A0A1(t+2)->AB; post-load aq1 (A2A3 of t) */              \
    SBAR;                                                                           \
    STG_A0(AB); STG_A1(AB);                                                         \
    SCHED0;                                                                         \
    CLUSTER(0, 1, aq0, b1);                                                         \
    SCHED0;                                                                         \
    LOAD_AQ(aq1, 1, ABa0, ABa1);                                                    \
    SCHED0;                                                                         \
    /* p2 (qm1,qn1): stage B2B3(t+2)->AB; pre-load b0r (B0B1 of t) */               \
    SBAR;                                                                           \
    STG_B2(AB); STG_B3(AB);                                                         \
    LOAD_BQ(b0r, 0, ABb0, ABb1);                                                    \
    SCHED0;                                                                         \
    CLUSTER(1, 1, aq1, b1);                                                         \
    SCHED0;                                                                         \
    /* p3 (qm1,qn0): vmcnt(4) forces <= t.p0 landed; post-load next tile's aq0,b0 */\
    VM4;                                                                            \
    SBAR;                                                                           \
    STG_A2(AB); STG_A3(AB);                                                         \
    SCHED0;                                                                         \
    CLUSTER(1, 0, aq1, b0r);                                                        \
    SCHED0;                                                                         \
    LOAD_AQ(aq0, 0, NBa0, NBa1);                                                    \
    LOAD_BQ(b0, 0, NBb0, NBb1);                                                     \
    SCHED0;                                                                         \
    gA_p += 64; gB_p += 64;                                                         \
  }

  for (int tt = 0; tt < 32; tt++) {
    TILE(0, 65536, bA00, bA01, bB00, bB01, bA10, bA11, bB10, bB11);
    TILE(65536, 0, bA10, bA11, bB10, bB11, bA00, bA01, bB00, bB01);
  }

  // epilogue: C/D layout col = lane&15, row = (lane>>4)*4 + j
#pragma unroll
  for (int mf = 0; mf < 8; mf++) {
#pragma unroll
    for (int nf = 0; nf < 4; nf++) {
      const int col  = n0 + wn * 64 + nf * 16 + fr;
      const int row0 = m0 + wm * 128 + mf * 16 + (lane >> 4) * 4;
      const float bv = bias[col];
#pragma unroll
      for (int j = 0; j < 4; j++)
        C[(size_t)(row0 + j) * N + col] = acc[mf][nf][j] + bv;
    }
  }
#undef TILE
#undef CLUSTER
#undef LOAD_AQ
#undef LOAD_BQ
#undef SBAR
#undef SCHED0
#undef VM4
#undef STG_A0
#undef STG_A1
#undef STG_A2
#undef STG_A3
#undef STG_B0
#undef STG_B1
#undef STG_B2
#undef STG_B3
}

extern "C" void kernel_launch(void* const* d_in, const int* in_sizes, int n_in,
                              void* d_out, int out_size, void* d_ws, size_t ws_size,
                              hipStream_t stream)
{
  const float* x         = (const float*)d_in[0];
  const float* centroids = (const float*)d_in[1];
  const int*   indices   = (const int*)d_in[2];
  const float* U         = (const float*)d_in[3];
  const float* S         = (const float*)d_in[4];
  const float* Vt        = (const float*)d_in[5];
  const float* wscale    = (const float*)d_in[6];
  const float* wbias     = (const float*)d_in[7];
  const float* bias      = (const float*)d_in[8];
  float* out = (float*)d_out;

  char* ws = (char*)d_ws;
  bf16* xb   = (bf16*)(ws);                          // 64 MB
  bf16* Wb   = (bf16*)(ws + 67108864);               // 32 MB
  bf16* Ub   = (bf16*)(ws + 100663296);              // 1 MB
  bf16* SVtT = (bf16*)(ws + 101711872);              // 1 MB

  convert_x_kernel<<<2048, 256, 0, stream>>>(x, xb, 8192 * 4096);
  prep_kernel<<<2048, 256, 0, stream>>>(U, S, Vt, Ub, SVtT);

  // W[o][i] = codebook(o,i)*wscale[o] + wbias[o] + sum_r Ub[o][r]*SVtT[i][r]
  dim3 gW(4096 / 128, 4096 / 128);
  gemm_wbuild<<<gW, 256, 0, stream>>>(Ub, SVtT, Wb, 4096, 4096, 128,
                                      indices, centroids, wscale, wbias);

  // out[t][o] = sum_i xb[t][i]*Wb[o][i] + bias[o]
  gemm256<<<512, 512, 131072, stream>>>(xb, Wb, out, bias);
}

// Round 11
// 279.918 us; speedup vs baseline: 1.1560x; 1.0301x over previous
//
#include <hip/hip_runtime.h>
#include <hip/hip_bf16.h>
#include <stdint.h>

using bf16 = __hip_bfloat16;
typedef __bf16 bf16x8 __attribute__((ext_vector_type(8)));
typedef float f32x4 __attribute__((ext_vector_type(4)));
typedef short short8 __attribute__((ext_vector_type(8)));

#define GLD_LDS16(gp, lp)                                                            \
  __builtin_amdgcn_global_load_lds(                                                  \
      (const __attribute__((address_space(1))) unsigned int*)(gp),                   \
      (__attribute__((address_space(3))) unsigned int*)(lp), 16, 0, 0)

// ---------------- fused prologue: SVtT transpose + Ub convert + x convert ----------------
// blocks [0,128):    SVtT[i][r] = S[r]*Vt[r][i] via padded-LDS 64x64 tile transpose
// blocks [128,384):  Ub = bf16(U)          (524288 elems, 8/thread)
// blocks [384,2432): xb = bf16(x)          (grid-stride, 8/thread)
__global__ __launch_bounds__(256) void prep_convert(const float* __restrict__ x,
                                                    bf16* __restrict__ xb, int n,
                                                    const float* __restrict__ U,
                                                    const float* __restrict__ S,
                                                    const float* __restrict__ Vt,
                                                    bf16* __restrict__ Ub,
                                                    bf16* __restrict__ SVtT)
{
  __shared__ float tile[64][65];   // +1 pad -> conflict-free column reads
  const int b = blockIdx.x;
  const int t = threadIdx.x;

  if (b < 128) {
    // ---- Vt transpose tile: i0 = (b>>1)*64, r0 = (b&1)*64 ----
    const int i0 = (b >> 1) * 64;
    const int r0 = (b & 1) * 64;
    const int lrow = t >> 4;          // 0..15
    const int lcol = (t & 15) * 4;    // 0,4,..,60
#pragma unroll
    for (int p = 0; p < 4; p++) {
      const int row = p * 16 + lrow;
      const float s = S[r0 + row];
      const float4 v = *(const float4*)(Vt + (size_t)(r0 + row) * 4096 + i0 + lcol);
      tile[row][lcol + 0] = v.x * s;
      tile[row][lcol + 1] = v.y * s;
      tile[row][lcol + 2] = v.z * s;
      tile[row][lcol + 3] = v.w * s;
    }
    __syncthreads();
    const int il = t >> 2;            // 0..63
    const int rq = (t & 3) * 16;      // 0,16,32,48
    union { bf16 h[16]; short8 v[2]; } u;
#pragma unroll
    for (int j = 0; j < 16; j++)
      u.h[j] = __float2bfloat16(tile[rq + j][il]);
    short8* dst = (short8*)(SVtT + (size_t)(i0 + il) * 128 + r0 + rq);
    dst[0] = u.v[0];
    dst[1] = u.v[1];
  } else if (b < 384) {
    // ---- Ub convert ----
    const int i = ((b - 128) * 256 + t) * 8;
    float4 a0 = *(const float4*)(U + i);
    float4 a1 = *(const float4*)(U + i + 4);
    union { bf16 h[8]; short8 v; } u;
    u.h[0] = __float2bfloat16(a0.x); u.h[1] = __float2bfloat16(a0.y);
    u.h[2] = __float2bfloat16(a0.z); u.h[3] = __float2bfloat16(a0.w);
    u.h[4] = __float2bfloat16(a1.x); u.h[5] = __float2bfloat16(a1.y);
    u.h[6] = __float2bfloat16(a1.z); u.h[7] = __float2bfloat16(a1.w);
    *(short8*)(Ub + i) = u.v;
  } else {
    // ---- x convert, grid-stride over 2048 logical blocks ----
    const int vb = b - 384;
    for (int i = (vb * 256 + t) * 8; i < n; i += 2048 * 256 * 8) {
      float4 a = *(const float4*)(x + i);
      float4 c = *(const float4*)(x + i + 4);
      union { bf16 h[8]; short8 v; } u;
      u.h[0] = __float2bfloat16(a.x); u.h[1] = __float2bfloat16(a.y);
      u.h[2] = __float2bfloat16(a.z); u.h[3] = __float2bfloat16(a.w);
      u.h[4] = __float2bfloat16(c.x); u.h[5] = __float2bfloat16(c.y);
      u.h[6] = __float2bfloat16(c.z); u.h[7] = __float2bfloat16(c.w);
      *(short8*)(xb + i) = u.v;
    }
  }
}

// ---------------- wbuild v2: 128x128, K=128 staged in ONE shot ----------------
__global__ __launch_bounds__(256, 2) void gemm_wbuild(const bf16* __restrict__ A,
                                                      const bf16* __restrict__ B,
                                                      bf16* __restrict__ Cb,
                                                      int M, int N, int K,
                                                      const int* __restrict__ indices,
                                                      const float* __restrict__ centroids,
                                                      const float* __restrict__ wscale,
                                                      const float* __restrict__ wbias)
{
  __shared__ bf16 As4[4 * 4096];   // 4 chunks x 128 rows x 32 k = 32 KB
  __shared__ bf16 Bs4[4 * 4096];   // 32 KB

  const int tid  = threadIdx.x;
  const int m0   = blockIdx.y * 128;
  const int n0   = blockIdx.x * 128;
  const int wid  = tid >> 6;
  const int lane = tid & 63;
  const int wm   = wid >> 1;
  const int wn   = wid & 1;
  const int kk   = (lane >> 4) * 8;
  const int fr   = lane & 15;

  const int sr = tid >> 2;          // 0..63
  const int sc = (tid & 3) * 8;     // 0,8,16,24
  const bf16* ga = A + (size_t)(m0 + sr) * 128 + sc;
  const bf16* gb = B + (size_t)(n0 + sr) * 128 + sc;

#pragma unroll
  for (int c = 0; c < 4; c++) {
    GLD_LDS16(ga + 32 * c,            &As4[c * 4096 + tid * 8]);
    GLD_LDS16(ga + 32 * c + 64 * 128, &As4[c * 4096 + 2048 + tid * 8]);
    GLD_LDS16(gb + 32 * c,            &Bs4[c * 4096 + tid * 8]);
    GLD_LDS16(gb + 32 * c + 64 * 128, &Bs4[c * 4096 + 2048 + tid * 8]);
  }
  __syncthreads();   // drains vmcnt -> all 64 KB staged

  f32x4 acc[4][4] = {};
#pragma unroll
  for (int c = 0; c < 4; c++) {
    bf16x8 af[4], bfr[4];
#pragma unroll
    for (int m = 0; m < 4; m++)
      af[m] = *(const bf16x8*)(&As4[c * 4096 + (wm * 64 + m * 16 + fr) * 32 + kk]);
#pragma unroll
    for (int n = 0; n < 4; n++)
      bfr[n] = *(const bf16x8*)(&Bs4[c * 4096 + (wn * 64 + n * 16 + fr) * 32 + kk]);
#pragma unroll
    for (int m = 0; m < 4; m++)
#pragma unroll
      for (int n = 0; n < 4; n++)
        acc[m][n] = __builtin_amdgcn_mfma_f32_16x16x32_bf16(af[m], bfr[n], acc[m][n], 0, 0, 0);
  }

#pragma unroll
  for (int m = 0; m < 4; m++) {
#pragma unroll
    for (int n = 0; n < 4; n++) {
      const int col  = n0 + wn * 64 + n * 16 + (lane & 15);
      const int rowb = m0 + wm * 64 + m * 16 + (lane >> 4) * 4;
#pragma unroll
      for (int j = 0; j < 4; j++) {
        const int row  = rowb + j;
        const int idxv = indices[row * 512 + (col >> 3)];
        const float cv = centroids[idxv * 8 + (col & 7)];
        const float w  = cv * wscale[row] + wbias[row] + acc[m][n][j];
        Cb[(size_t)row * N + col] = __float2bfloat16(w);
      }
    }
  }
}

// ---------------- main 256x256 pipelined GEMM, 16x16x32 MFMA (verbatim R10) ----------------
// R6 schedule (proven race-free) + base-pointer/literal-offset ds_read addressing.
// R9 lesson: 32x32x16 MFMA = 4-way bank conflict under this layout — do not use.
// R7 lesson: do NOT remove p2's b0r re-read or move aq1 to p0-post.
__global__ __launch_bounds__(512, 2) void gemm256(const bf16* __restrict__ A,
                                                  const bf16* __restrict__ B,
                                                  float* __restrict__ C,
                                                  const float* __restrict__ bias)
{
  extern __shared__ char smem[];     // [2][A 32KB | B 32KB] = 128 KiB
  constexpr int K = 4096;
  constexpr int N = 4096;

  const int tid  = threadIdx.x;
  const int lane = tid & 63;
  const int wave = tid >> 6;
  const int wm   = wave >> 2;        // 0..1
  const int wn   = wave & 3;         // 0..3
  const int fr   = lane & 15;
  const int kk   = (lane >> 4) * 8;
  const int swx  = (fr & 7) << 4;    // read-side swizzle

  // XCD-aware swizzle, 8x8 tile group per XCD: grid m=32, n=16
  const int bid = blockIdx.x;
  const int xcd = bid & 7;
  const int idx = bid >> 3;
  const int mi  = (xcd & 3) * 8 + (idx & 7);
  const int ni  = (xcd >> 2) * 8 + (idx >> 3);
  const int m0  = mi * 256;
  const int n0  = ni * 256;

  // stage bases: inverse-swizzled global source for linear global_load_lds dest.
  const int pA = tid * 16;
  const int rA = pA >> 7;
  const int kA = ((pA ^ ((rA & 7) << 4)) & 127) >> 1;
  const bf16* gA0 = A + (size_t)(m0 + rA) * K + kA;
  const int pB = (tid >> 8) * 8192 + (tid & 255) * 16;
  const int rB = pB >> 7;
  const int kB = ((pB ^ ((rB & 7) << 4)) & 127) >> 1;
  const bf16* gB0 = B + (size_t)(n0 + rB) * K + kB;

  f32x4 acc[8][4] = {};

  // loop-invariant LDS read bases (8 pointers; ks = k-half 0/1, buf 0/1)
  const int laneK0 = fr * 128 + ((kk * 2) ^ swx);
  const int laneK1 = fr * 128 + ((64 + kk * 2) ^ swx);
  const char* bA00 = smem + wm * 16384 + laneK0;            // buf0, ks0
  const char* bA01 = smem + wm * 16384 + laneK1;            // buf0, ks1
  const char* bA10 = bA00 + 65536;                          // buf1
  const char* bA11 = bA01 + 65536;
  const char* bB00 = smem + 32768 + wn * 8192 + laneK0;
  const char* bB01 = smem + 32768 + wn * 8192 + laneK1;
  const char* bB10 = bB00 + 65536;
  const char* bB11 = bB01 + 65536;

#define STG_A0(bo) GLD_LDS16(gA_p,                   smem + (bo) + pA)
#define STG_A1(bo) GLD_LDS16(gA_p + 128 * 4096,      smem + (bo) + pA + 16384)
#define STG_A2(bo) GLD_LDS16(gA_p +  64 * 4096,      smem + (bo) + pA + 8192)
#define STG_A3(bo) GLD_LDS16(gA_p + 192 * 4096,      smem + (bo) + pA + 24576)
#define STG_B0(bo) GLD_LDS16(gB_p,                   smem + (bo) + 32768 + pB)
#define STG_B1(bo) GLD_LDS16(gB_p + 128 * 4096,      smem + (bo) + 32768 + pB + 16384)
#define STG_B2(bo) GLD_LDS16(gB_p + 64 +  32 * 4096, smem + (bo) + 32768 + pB + 4096)
#define STG_B3(bo) GLD_LDS16(gB_p + 64 + 160 * 4096, smem + (bo) + 32768 + pB + 20480)

#define LOAD_AQ(dst, qm, P0, P1)                                                    \
  _Pragma("unroll") for (int mm = 0; mm < 4; mm++)                                  \
    _Pragma("unroll") for (int ks = 0; ks < 2; ks++)                                \
      dst[mm][ks] = *(const bf16x8*)((ks ? (P1) : (P0)) +                           \
                                     ((qm) * 8192 + mm * 2048));

#define LOAD_BQ(dst, qn, P0, P1)                                                    \
  _Pragma("unroll") for (int nn = 0; nn < 2; nn++)                                  \
    _Pragma("unroll") for (int ks = 0; ks < 2; ks++)                                \
      dst[nn][ks] = *(const bf16x8*)((ks ? (P1) : (P0)) +                           \
                                     ((qn) * 4096 + nn * 2048));

#define CLUSTER(qm, qn, av, bv)                                                     \
  __builtin_amdgcn_s_setprio(1);                                                    \
  _Pragma("unroll") for (int ks = 0; ks < 2; ks++)                                  \
    _Pragma("unroll") for (int mm = 0; mm < 4; mm++)                                \
      _Pragma("unroll") for (int nn = 0; nn < 2; nn++)                              \
        acc[(qm) * 4 + mm][(qn) * 2 + nn] =                                         \
            __builtin_amdgcn_mfma_f32_16x16x32_bf16(                                \
                av[mm][ks], bv[nn][ks], acc[(qm) * 4 + mm][(qn) * 2 + nn],          \
                0, 0, 0);                                                           \
  __builtin_amdgcn_s_setprio(0);

#define SBAR   __builtin_amdgcn_s_barrier()
#define SCHED0 __builtin_amdgcn_sched_barrier(0)
#define VM4    asm volatile("s_waitcnt vmcnt(4)" ::: "memory")

  bf16x8 aq0[4][2], aq1[4][2], b0[2][2], b1[2][2], b0r[2][2];

  // prologue: tile0 all 8 slots -> buf0; tile1 (k=64) A0A1/B2B3/A2A3 -> buf1.
  GLD_LDS16(gA0,                  smem + pA);
  GLD_LDS16(gA0 + 128 * 4096,     smem + pA + 16384);
  GLD_LDS16(gB0,                  smem + 32768 + pB);
  GLD_LDS16(gB0 + 128 * 4096,     smem + 32768 + pB + 16384);
  GLD_LDS16(gB0 +  32 * 4096,     smem + 32768 + pB + 4096);
  GLD_LDS16(gB0 + 160 * 4096,     smem + 32768 + pB + 20480);
  GLD_LDS16(gA0 +  64 * 4096,     smem + pA + 8192);
  GLD_LDS16(gA0 + 192 * 4096,     smem + pA + 24576);
  GLD_LDS16(gA0 + 64,             smem + 65536 + pA);
  GLD_LDS16(gA0 + 64 + 128 * 4096, smem + 65536 + pA + 16384);
  GLD_LDS16(gB0 + 64 +  32 * 4096, smem + 65536 + 32768 + pB + 4096);
  GLD_LDS16(gB0 + 64 + 160 * 4096, smem + 65536 + 32768 + pB + 20480);
  GLD_LDS16(gA0 + 64 +  64 * 4096, smem + 65536 + pA + 8192);
  GLD_LDS16(gA0 + 64 + 192 * 4096, smem + 65536 + pA + 24576);
  asm volatile("s_waitcnt vmcnt(6)" ::: "memory");
  SBAR;
  LOAD_AQ(aq0, 0, bA00, bA01);
  LOAD_BQ(b0, 0, bB00, bB01);
  SCHED0;

  const bf16* gA_p = gA0 + 128;        // tile t+2 (t=0) k offset
  const bf16* gB_p = gB0 + 64;         // tile t+1 (t=0) k offset

#define TILE(AB, NB, ABa0, ABa1, ABb0, ABb1, NBa0, NBa1, NBb0, NBb1)                \
  {                                                                                 \
    /* p0 (qm0,qn0): stage B0B1(t+1)->NB; pre-load b1 (B2B3 of t) */                \
    SBAR;                                                                           \
    STG_B0(NB); STG_B1(NB);                                                         \
    LOAD_BQ(b1, 1, ABb0, ABb1);                                                     \
    SCHED0;                                                                         \
    CLUSTER(0, 0, aq0, b0);                                                         \
    SCHED0;                                                                         \
    /* p1 (qm0,qn1): stage A0A1(t+2)->AB; post-load aq1 (A2A3 of t) */              \
    SBAR;                                                                           \
    STG_A0(AB); STG_A1(AB);                                                         \
    SCHED0;                                                                         \
    CLUSTER(0, 1, aq0, b1);                                                         \
    SCHED0;                                                                         \
    LOAD_AQ(aq1, 1, ABa0, ABa1);                                                    \
    SCHED0;                                                                         \
    /* p2 (qm1,qn1): stage B2B3(t+2)->AB; pre-load b0r (B0B1 of t) */               \
    SBAR;                                                                           \
    STG_B2(AB); STG_B3(AB);                                                         \
    LOAD_BQ(b0r, 0, ABb0, ABb1);                                                    \
    SCHED0;                                                                         \
    CLUSTER(1, 1, aq1, b1);                                                         \
    SCHED0;                                                                         \
    /* p3 (qm1,qn0): vmcnt(4) forces <= t.p0 landed; post-load next tile's aq0,b0 */\
    VM4;                                                                            \
    SBAR;                                                                           \
    STG_A2(AB); STG_A3(AB);                                                         \
    SCHED0;                                                                         \
    CLUSTER(1, 0, aq1, b0r);                                                        \
    SCHED0;                                                                         \
    LOAD_AQ(aq0, 0, NBa0, NBa1);                                                    \
    LOAD_BQ(b0, 0, NBb0, NBb1);                                                     \
    SCHED0;                                                                         \
    gA_p += 64; gB_p += 64;                                                         \
  }

  for (int tt = 0; tt < 32; tt++) {
    TILE(0, 65536, bA00, bA01, bB00, bB01, bA10, bA11, bB10, bB11);
    TILE(65536, 0, bA10, bA11, bB10, bB11, bA00, bA01, bB00, bB01);
  }

  // epilogue: C/D layout col = lane&15, row = (lane>>4)*4 + j
#pragma unroll
  for (int mf = 0; mf < 8; mf++) {
#pragma unroll
    for (int nf = 0; nf < 4; nf++) {
      const int col  = n0 + wn * 64 + nf * 16 + fr;
      const int row0 = m0 + wm * 128 + mf * 16 + (lane >> 4) * 4;
      const float bv = bias[col];
#pragma unroll
      for (int j = 0; j < 4; j++)
        C[(size_t)(row0 + j) * N + col] = acc[mf][nf][j] + bv;
    }
  }
#undef TILE
#undef CLUSTER
#undef LOAD_AQ
#undef LOAD_BQ
#undef SBAR
#undef SCHED0
#undef VM4
#undef STG_A0
#undef STG_A1
#undef STG_A2
#undef STG_A3
#undef STG_B0
#undef STG_B1
#undef STG_B2
#undef STG_B3
}

extern "C" void kernel_launch(void* const* d_in, const int* in_sizes, int n_in,
                              void* d_out, int out_size, void* d_ws, size_t ws_size,
                              hipStream_t stream)
{
  const float* x         = (const float*)d_in[0];
  const float* centroids = (const float*)d_in[1];
  const int*   indices   = (const int*)d_in[2];
  const float* U         = (const float*)d_in[3];
  const float* S         = (const float*)d_in[4];
  const float* Vt        = (const float*)d_in[5];
  const float* wscale    = (const float*)d_in[6];
  const float* wbias     = (const float*)d_in[7];
  const float* bias      = (const float*)d_in[8];
  float* out = (float*)d_out;

  char* ws = (char*)d_ws;
  bf16* xb   = (bf16*)(ws);                          // 64 MB
  bf16* Wb   = (bf16*)(ws + 67108864);               // 32 MB
  bf16* Ub   = (bf16*)(ws + 100663296);              // 1 MB
  bf16* SVtT = (bf16*)(ws + 101711872);              // 1 MB

  // fused prologue: SVtT transpose (128 blk) + Ub (256 blk) + xb (2048 blk)
  prep_convert<<<2432, 256, 0, stream>>>(x, xb, 8192 * 4096, U, S, Vt, Ub, SVtT);

  // W[o][i] = codebook(o,i)*wscale[o] + wbias[o] + sum_r Ub[o][r]*SVtT[i][r]
  dim3 gW(4096 / 128, 4096 / 128);
  gemm_wbuild<<<gW, 256, 0, stream>>>(Ub, SVtT, Wb, 4096, 4096, 128,
                                      indices, centroids, wscale, wbias);

  // out[t][o] = sum_i xb[t][i]*Wb[o][i] + bias[o]
  gemm256<<<512, 512, 131072, stream>>>(xb, Wb, out, bias);
}